// Round 13
// baseline (789.197 us; speedup 1.0000x reference)
//
#include <hip/hip_runtime.h>
#include <stdint.h>
#include <stddef.h>

// ---------------------------------------------------------------------------
// FlaxMptAttention fused block for MI355X (gfx950)
// B=2, S=2048, D=2048, H=16, d_head=128
// Pipeline: cvt(x) / transpose-cvt(w_qkv, wo) -> QKV GEMM (bf16 out)
//           -> LN(q,k) -> transpose(v) -> flash attention -> out-proj GEMM
// R13: GEMMs + helpers BYTE-FROZEN at R12 (passing, 357.3us).
//      attn replaced by a RACE-FREE-BY-CONSTRUCTION design: K/V/bias read
//      directly from global (L2-resident panels), no __syncthreads, no
//      global_load_lds, no inline waitcnt; only wave-private p_lds remains.
//      Math path (softmax/cvt_pk/MFMA-ones/mask) copied verbatim from the
//      proven kernel. R6-R10 showed the old sync machinery was fragile;
//      this removes the machinery instead of perturbing it.
// ---------------------------------------------------------------------------

typedef __attribute__((ext_vector_type(8))) short bf16x8;
typedef __attribute__((ext_vector_type(4))) float f32x4;

#define MFMA16(a, b, c) __builtin_amdgcn_mfma_f32_16x16x32_bf16((a), (b), (c), 0, 0, 0)

__device__ __forceinline__ void async_copy16(void* lds, const void* g) {
  __builtin_amdgcn_global_load_lds(
      (const __attribute__((address_space(1))) void*)g,
      (__attribute__((address_space(3))) void*)lds, 16, 0, 0);
}

__device__ __forceinline__ short f2bf(float f) {
  union { float f; uint32_t u; } v; v.f = f;
  uint32_t r = (v.u + 0x7fffu + ((v.u >> 16) & 1u)) >> 16;
  return (short)(uint16_t)r;
}

__device__ __forceinline__ float bf2f(short s) {
  union { float f; uint32_t u; } v;
  v.u = ((uint32_t)(uint16_t)s) << 16;
  return v.f;
}

#define ATT_SCALE 0.08838834764831845f
#define VMDRAIN asm volatile("s_waitcnt vmcnt(0)" ::: "memory")

// ---------------------------------------------------------------------------
// elementwise fp32 -> bf16 (exact multiple of 2048 elems per block)
__global__ __launch_bounds__(256) void cvt_f32_bf16(const float* __restrict__ in,
                                                    short* __restrict__ out) {
  size_t i = ((size_t)blockIdx.x * 256 + threadIdx.x) * 8;
  f32x4 a = *(const f32x4*)(in + i);
  f32x4 b = *(const f32x4*)(in + i + 4);
  bf16x8 o;
#pragma unroll
  for (int j = 0; j < 4; ++j) { o[j] = f2bf(a[j]); o[4 + j] = f2bf(b[j]); }
  *(bf16x8*)(out + i) = o;
}

// ---------------------------------------------------------------------------
// in[R][C] fp32 -> out[C][R] bf16, 64x64 LDS tiles
__global__ __launch_bounds__(256) void transpose_cvt(const float* __restrict__ in,
                                                     short* __restrict__ out,
                                                     int R, int C) {
  __shared__ float t[64][65];
  const int tid = threadIdx.x;
  const int c0 = blockIdx.x * 64, r0 = blockIdx.y * 64;
#pragma unroll
  for (int i = 0; i < 16; ++i) {
    int idx = i * 256 + tid;
    int r = idx >> 6, c = idx & 63;
    t[r][c] = in[(size_t)(r0 + r) * C + c0 + c];
  }
  __syncthreads();
#pragma unroll
  for (int i = 0; i < 16; ++i) {
    int idx = i * 256 + tid;
    int cc = idx >> 6, rr = idx & 63;
    out[(size_t)(c0 + cc) * R + r0 + rr] = f2bf(t[rr][cc]);
  }
}

// ---------------------------------------------------------------------------
// v part of qkv bf16 [4096][6144] -> vt bf16 [b][h][128][2048]
__global__ __launch_bounds__(256) void transpose_v_bf(const short* __restrict__ qkv,
                                                      short* __restrict__ vt) {
  __shared__ short t[64][65];
  const int tid = threadIdx.x;
  const int d0 = blockIdx.x * 64;   // 0 or 64
  const int s0 = blockIdx.y * 64;   // 32 tiles
  const int bh = blockIdx.z;
  const int b = bh >> 4, h = bh & 15;
#pragma unroll
  for (int i = 0; i < 16; ++i) {
    int idx = i * 256 + tid;
    int r = idx >> 6, c = idx & 63;   // r = s-local, c = d-local
    t[r][c] = qkv[(size_t)(b * 2048 + s0 + r) * 6144 + 4096 + h * 128 + d0 + c];
  }
  __syncthreads();
#pragma unroll
  for (int i = 0; i < 16; ++i) {
    int idx = i * 256 + tid;
    int dd = idx >> 6, ss = idx & 63;
    vt[((size_t)(bh * 128 + d0 + dd)) * 2048 + s0 + ss] = t[ss][dd];
  }
}

// ---------------------------------------------------------------------------
// LayerNorm over full D=2048 for q and k slices of qkv bf16, write bf16.
// q output is pre-scaled by 1/sqrt(d_head) (folded attention scale).
__global__ __launch_bounds__(256) void ln_qk(const short* __restrict__ qkv,
                                             const float* __restrict__ qsc,
                                             const float* __restrict__ ksc,
                                             short* __restrict__ q_bf,
                                             short* __restrict__ k_bf) {
  __shared__ float redS[2][4], redQ[2][4];
  const int row = blockIdx.x, tid = threadIdx.x;
  const int lane = tid & 63, wave = tid >> 6;
  const short* base = qkv + (size_t)row * 6144;
#pragma unroll
  for (int part = 0; part < 2; ++part) {
    const short* p = base + part * 2048 + tid * 8;
    bf16x8 v8 = *(const bf16x8*)p;
    float f[8];
#pragma unroll
    for (int j = 0; j < 8; ++j) f[j] = bf2f(v8[j]);
    float s = 0.f, sq = 0.f;
#pragma unroll
    for (int j = 0; j < 8; ++j) { s += f[j]; sq += f[j] * f[j]; }
#pragma unroll
    for (int d = 1; d < 64; d <<= 1) { s += __shfl_xor(s, d); sq += __shfl_xor(sq, d); }
    if (lane == 0) { redS[part][wave] = s; redQ[part][wave] = sq; }
    __syncthreads();
    float tot  = redS[part][0] + redS[part][1] + redS[part][2] + redS[part][3];
    float totq = redQ[part][0] + redQ[part][1] + redQ[part][2] + redQ[part][3];
    float mean = tot * (1.f / 2048.f);
    float var  = totq * (1.f / 2048.f) - mean * mean;
    float rstd = rsqrtf(var + 1e-6f) * (part == 0 ? ATT_SCALE : 1.0f);
    const float* scp = (part == 0 ? qsc : ksc) + tid * 8;
    f32x4 s0 = *(const f32x4*)scp;
    f32x4 s1 = *(const f32x4*)(scp + 4);
    bf16x8 o;
#pragma unroll
    for (int j = 0; j < 4; ++j) {
      o[j]     = f2bf((f[j] - mean) * rstd * s0[j]);
      o[4 + j] = f2bf((f[4 + j] - mean) * rstd * s1[j]);
    }
    short* outp = (part == 0 ? q_bf : k_bf) + (size_t)row * 2048 + tid * 8;
    *(bf16x8*)outp = o;
  }
}

// ---------------------------------------------------------------------------
// C[M][N] = A[M][K] @ BT[N][K]^T + bias[N]; bf16 inputs, OutT out
// 128x128 tile, BK=64, 4 waves (2x2), 16x16x32 MFMA.
// 128B LDS rows XOR-swizzled: write slot (c&7) holds global chunk
// (c&7)^(row&7); read slot g^(row&7) yields chunk g. 2-way bank aliasing
// only (free, m136). Fragments loaded per-K-half to hold VGPR ~165.
template <typename OutT>
__global__ __launch_bounds__(256, 2) void gemm_bt_bias(const short* __restrict__ A,
                                                       const short* __restrict__ BT,
                                                       const float* __restrict__ bias,
                                                       OutT* __restrict__ C,
                                                       int M, int N, int K) {
  __shared__ alignas(16) short a_lds[128 * 64];
  __shared__ alignas(16) short b_lds[128 * 64];
  const int tid = threadIdx.x;
  const int lane = tid & 63, wave = tid >> 6;
  const int wr = wave >> 1, wc = wave & 1;
  const int tn = blockIdx.x, tm = blockIdx.y;
  const int r15 = lane & 15, hi = lane >> 4;

  const short* Ab = A + (size_t)tm * 128 * K;
  const short* Bb = BT + (size_t)tn * 128 * K;

  f32x4 acc[4][4];
  const f32x4 Z = {0.f, 0.f, 0.f, 0.f};
#pragma unroll
  for (int m = 0; m < 4; ++m)
#pragma unroll
    for (int n = 0; n < 4; ++n) acc[m][n] = Z;

  for (int k0 = 0; k0 < K; k0 += 64) {
    __syncthreads();
#pragma unroll
    for (int j = 0; j < 4; ++j) {
      int c = j * 256 + tid;              // 1024 slots of 8 elems
      int row = c >> 3;                   // 128 rows x 8 chunks
      int ch = (c & 7) ^ (row & 7);       // pre-swizzled source chunk
      async_copy16(&a_lds[c << 3], Ab + (size_t)row * K + k0 + (ch << 3));
      async_copy16(&b_lds[c << 3], Bb + (size_t)row * K + k0 + (ch << 3));
    }
    VMDRAIN;
    __syncthreads();
#pragma unroll
    for (int kk = 0; kk < 2; ++kk) {
      bf16x8 af[4], bfr[4];
#pragma unroll
      for (int m = 0; m < 4; ++m) {
        int row = wr * 64 + m * 16 + r15;
        af[m] = *(const bf16x8*)&a_lds[row * 64 + (((kk * 4 + hi) ^ (row & 7)) << 3)];
      }
#pragma unroll
      for (int n = 0; n < 4; ++n) {
        int row = wc * 64 + n * 16 + r15;
        bfr[n] = *(const bf16x8*)&b_lds[row * 64 + (((kk * 4 + hi) ^ (row & 7)) << 3)];
      }
#pragma unroll
      for (int m = 0; m < 4; ++m)
#pragma unroll
        for (int n = 0; n < 4; ++n)
          acc[m][n] = MFMA16(af[m], bfr[n], acc[m][n]);
    }
  }

  const int r0 = tm * 128 + wr * 64;
  const int c0 = tn * 128 + wc * 64;
#pragma unroll
  for (int n = 0; n < 4; ++n) {
    float bv = bias[c0 + n * 16 + r15];
#pragma unroll
    for (int m = 0; m < 4; ++m) {
#pragma unroll
      for (int r = 0; r < 4; ++r) {
        float val = acc[m][n][r] + bv;
        size_t idx = (size_t)(r0 + m * 16 + hi * 4 + r) * N + c0 + n * 16 + r15;
        if constexpr (sizeof(OutT) == 2) C[idx] = (OutT)f2bf(val);
        else                             C[idx] = val;
      }
    }
  }
}

// ---------------------------------------------------------------------------
// Flash attention v2: block = (qt, h, b), 4 INDEPENDENT waves x 16 q-rows,
// KV tile = 64. K/V/bias read directly from global (L2-resident panels);
// NO __syncthreads, NO global_load_lds, NO inline waitcnt. Only wave-private
// p_lds (same-wave DS ordering, proven pattern). Math path verbatim from the
// validated kernel: folded 1/sqrt(d) in q, diag-peeled causal mask, cvt_pk
// P pack, MFMA-ones rowsum, online softmax on 16-lane groups.
// q_bf/k_bf: [4096][2048] bf16 (col = h*128+dd); vt: [b][h][128][2048] bf16
__global__ __launch_bounds__(256) void attn_fwd2(const short* __restrict__ q_bf,
                                                 const short* __restrict__ k_bf,
                                                 const short* __restrict__ vt,
                                                 const float* __restrict__ abias,
                                                 const int* __restrict__ amask,
                                                 short* __restrict__ out_bf) {
  __shared__ alignas(16) short p_lds[4][16 * 64];

  const int tid = threadIdx.x, lane = tid & 63, wave = tid >> 6;
  const int qt = 31 - blockIdx.x;   // heavy (long) blocks dispatch first
  const int h = blockIdx.y, b = blockIdx.z;
  const int r15 = lane & 15, hi = lane >> 4;

  // Q fragments held in registers (16 rows per wave); q pre-scaled by 1/sqrt(d)
  const int qrow = b * 2048 + qt * 64 + wave * 16 + r15;
  bf16x8 qf[4];
#pragma unroll
  for (int kb = 0; kb < 4; ++kb)
    qf[kb] = *(const bf16x8*)(q_bf + (size_t)qrow * 2048 + h * 128 + kb * 32 + hi * 8);

  f32x4 O[8];
  const f32x4 Z = {0.f, 0.f, 0.f, 0.f};
#pragma unroll
  for (int n = 0; n < 8; ++n) O[n] = Z;
  f32x4 Ol = Z;                 // running row-sum of exp (all cols identical)
  float m_run[4];
#pragma unroll
  for (int r = 0; r < 4; ++r) m_run[r] = -3e38f;

  const short one_bf = (short)0x3F80;  // bf16 1.0
  const bf16x8 ones_f = {one_bf, one_bf, one_bf, one_bf,
                         one_bf, one_bf, one_bf, one_bf};
  const int qg0 = qt * 64 + wave * 16 + hi * 4;
  const int ntiles = qt + 1;

  // Per-(b,h) base pointers; K panel 512KB, V panel 512KB -> L2-resident.
  const short* Kbase = k_bf + ((size_t)(b * 2048)) * 2048 + h * 128;
  const short* Vbase = vt + ((size_t)((b * 16 + h) * 128)) * 2048;
  const float* Bbase = abias + (size_t)h * 2048;
  const int*   Mbase = amask + (size_t)b * 2048;

  for (int kt = 0; kt < ntiles; ++kt) {
    // ---- QK^T: S[16q][64k] per wave, K fragments straight from global ----
    f32x4 s[4];
#pragma unroll
    for (int ks = 0; ks < 4; ++ks) {
      s[ks] = Z;
      const int krow = kt * 64 + ks * 16 + r15;
      const short* kp = Kbase + (size_t)krow * 2048;
#pragma unroll
      for (int kb = 0; kb < 4; ++kb) {
        bf16x8 kf = *(const bf16x8*)(kp + (kb * 4 + hi) * 8);
        s[ks] = MFMA16(qf[kb], kf, s[ks]);
      }
    }

    // ---- bias + padding mask (+ causal mask only on the diagonal tile) ----
    if (kt == qt) {
#pragma unroll
      for (int ks = 0; ks < 4; ++ks) {
        int kg = kt * 64 + ks * 16 + r15;
        float bb = Bbase[kg];
        if (Mbase[kg] == 0) bb = -1e30f;
#pragma unroll
        for (int r = 0; r < 4; ++r) {
          float v = s[ks][r] + bb;
          if (kg > qg0 + r) v = -1e30f;
          s[ks][r] = v;
        }
      }
    } else {
#pragma unroll
      for (int ks = 0; ks < 4; ++ks) {
        int kg = kt * 64 + ks * 16 + r15;
        float bb = Bbase[kg];
        if (Mbase[kg] == 0) bb = -1e30f;
#pragma unroll
        for (int r = 0; r < 4; ++r) s[ks][r] += bb;
      }
    }

    // ---- online softmax (rows live on 16-lane groups) ----
    float corr[4];
#pragma unroll
    for (int r = 0; r < 4; ++r) {
      float mx = fmaxf(fmaxf(s[0][r], s[1][r]), fmaxf(s[2][r], s[3][r]));
      mx = fmaxf(mx, __shfl_xor(mx, 1));
      mx = fmaxf(mx, __shfl_xor(mx, 2));
      mx = fmaxf(mx, __shfl_xor(mx, 4));
      mx = fmaxf(mx, __shfl_xor(mx, 8));
      float mn = fmaxf(m_run[r], mx);
      corr[r] = __expf(m_run[r] - mn);
      m_run[r] = mn;
#pragma unroll
      for (int ks = 0; ks < 4; ++ks) s[ks][r] = __expf(s[ks][r] - mn);
    }
#pragma unroll
    for (int r = 0; r < 4; ++r) {
      Ol[r] *= corr[r];
#pragma unroll
      for (int n = 0; n < 8; ++n) O[n][r] *= corr[r];
    }

    // ---- P -> per-wave LDS (swizzled) via cvt_pk, reload as A-fragments ----
    short* pw = &p_lds[wave][0];
#pragma unroll
    for (int r = 0; r < 4; ++r) {
      int q = hi * 4 + r;
      int qs = (q & 7) << 3;
      uint32_t pk0, pk1;
      asm("v_cvt_pk_bf16_f32 %0, %1, %2" : "=v"(pk0) : "v"(s[0][r]), "v"(s[1][r]));
      asm("v_cvt_pk_bf16_f32 %0, %1, %2" : "=v"(pk1) : "v"(s[2][r]), "v"(s[3][r]));
      pw[q * 64 + ((r15) ^ qs)]      = (short)pk0;
      pw[q * 64 + ((16 + r15) ^ qs)] = (short)(pk0 >> 16);
      pw[q * 64 + ((32 + r15) ^ qs)] = (short)pk1;
      pw[q * 64 + ((48 + r15) ^ qs)] = (short)(pk1 >> 16);
    }

    bf16x8 pf[2];
#pragma unroll
    for (int kb = 0; kb < 2; ++kb)
      pf[kb] = *(const bf16x8*)&pw[r15 * 64 + ((kb * 32 + hi * 8) ^ ((r15 & 7) << 3))];

    // ---- PV: O[16q][128d] += P @ V, V fragments straight from global ----
#pragma unroll
    for (int n = 0; n < 8; ++n) {
      const int vrow = n * 16 + r15;    // d index
      const short* vp = Vbase + (size_t)vrow * 2048 + kt * 64;
#pragma unroll
      for (int kb = 0; kb < 2; ++kb) {
        bf16x8 vf = *(const bf16x8*)(vp + (kb * 4 + hi) * 8);
        O[n] = MFMA16(pf[kb], vf, O[n]);
      }
    }
    Ol = MFMA16(pf[0], ones_f, Ol);
    Ol = MFMA16(pf[1], ones_f, Ol);
  }

  float inv[4];
#pragma unroll
  for (int r = 0; r < 4; ++r) inv[r] = 1.0f / Ol[r];
  const int orow = b * 2048 + qt * 64 + wave * 16;
#pragma unroll
  for (int n = 0; n < 8; ++n)
#pragma unroll
    for (int r = 0; r < 4; ++r)
      out_bf[(size_t)(orow + hi * 4 + r) * 2048 + h * 128 + n * 16 + r15] =
          f2bf(O[n][r] * inv[r]);
}

// ---------------------------------------------------------------------------
extern "C" void kernel_launch(void* const* d_in, const int* in_sizes, int n_in,
                              void* d_out, int out_size, void* d_ws, size_t ws_size,
                              hipStream_t stream) {
  const float* x     = (const float*)d_in[0];
  const float* abias = (const float*)d_in[1];
  const int*   amask = (const int*)d_in[2];
  const float* w_qkv = (const float*)d_in[3];
  const float* b_qkv = (const float*)d_in[4];
  const float* wo    = (const float*)d_in[5];
  const float* b_wo  = (const float*)d_in[6];
  const float* q_ln  = (const float*)d_in[7];
  const float* k_ln  = (const float*)d_in[8];
  float* out = (float*)d_out;

  char* ws = (char*)d_ws;
  short* x_bf   = (short*)(ws);                  // 16.78 MB  [4096][2048]
  short* wqkvT  = (short*)(ws + 16777216);       // 25.17 MB  [6144][2048]
  short* woT    = (short*)(ws + 41943040);       //  8.39 MB  [2048][2048]
  short* q_bf   = (short*)(ws + 50331648);       // 16.78 MB
  short* k_bf   = (short*)(ws + 67108864);       // 16.78 MB
  short* vt     = (short*)(ws + 83886080);       // 16.78 MB  [b][h][128][2048]
  short* out_bf = (short*)(ws + 100663296);      // 16.78 MB
  short* qkv_bf = (short*)(ws + 117440512);      // 50.33 MB  [4096][6144] bf16
  // total = 167,772,160 bytes

  cvt_f32_bf16<<<4096, 256, 0, stream>>>(x, x_bf);
  transpose_cvt<<<dim3(96, 32), 256, 0, stream>>>(w_qkv, wqkvT, 2048, 6144);
  transpose_cvt<<<dim3(32, 32), 256, 0, stream>>>(wo, woT, 2048, 2048);
  gemm_bt_bias<short><<<dim3(48, 32), 256, 0, stream>>>(x_bf, wqkvT, b_qkv, qkv_bf,
                                                        4096, 6144, 2048);
  ln_qk<<<4096, 256, 0, stream>>>(qkv_bf, q_ln, k_ln, q_bf, k_bf);
  transpose_v_bf<<<dim3(2, 32, 32), 256, 0, stream>>>(qkv_bf, vt);
  attn_fwd2<<<dim3(32, 16, 2), 256, 0, stream>>>(q_bf, k_bf, vt, abias, amask, out_bf);
  gemm_bt_bias<float><<<dim3(16, 32), 256, 0, stream>>>(out_bf, woT, b_wo, out,
                                                        4096, 2048, 2048);
}

// Round 14
// 357.275 us; speedup vs baseline: 2.2089x; 2.2089x over previous
//
#include <hip/hip_runtime.h>
#include <stdint.h>
#include <stddef.h>

// ---------------------------------------------------------------------------
// FlaxMptAttention fused block for MI355X (gfx950)
// B=2, S=2048, D=2048, H=16, d_head=128
// Pipeline: cvt(x) / transpose-cvt(w_qkv, wo) -> QKV GEMM (bf16 out)
//           -> LN(q,k) -> transpose(v) -> flash attention -> out-proj GEMM
// R14: REVERT to R12 verbatim (passing, 357.3us — best validated build).
//      R13's sync-free attn (direct-global K/V fragments) passed but ran
//      3.9x slower: per-lane MFMA fragment reads are scatter-shaped (rows
//      4KB apart) — they must be fed from LDS via coalesced global_load_lds.
//      attn_fwd byte-frozen at the R4/R11 form; GEMMs at BK=64 swizzled.
// ---------------------------------------------------------------------------

typedef __attribute__((ext_vector_type(8))) short bf16x8;
typedef __attribute__((ext_vector_type(4))) float f32x4;

#define MFMA16(a, b, c) __builtin_amdgcn_mfma_f32_16x16x32_bf16((a), (b), (c), 0, 0, 0)

__device__ __forceinline__ void async_copy16(void* lds, const void* g) {
  __builtin_amdgcn_global_load_lds(
      (const __attribute__((address_space(1))) void*)g,
      (__attribute__((address_space(3))) void*)lds, 16, 0, 0);
}

__device__ __forceinline__ short f2bf(float f) {
  union { float f; uint32_t u; } v; v.f = f;
  uint32_t r = (v.u + 0x7fffu + ((v.u >> 16) & 1u)) >> 16;
  return (short)(uint16_t)r;
}

__device__ __forceinline__ float bf2f(short s) {
  union { float f; uint32_t u; } v;
  v.u = ((uint32_t)(uint16_t)s) << 16;
  return v.f;
}

#define ATT_SCALE 0.08838834764831845f
#define VMDRAIN asm volatile("s_waitcnt vmcnt(0)" ::: "memory")

// ---------------------------------------------------------------------------
// elementwise fp32 -> bf16 (exact multiple of 2048 elems per block)
__global__ __launch_bounds__(256) void cvt_f32_bf16(const float* __restrict__ in,
                                                    short* __restrict__ out) {
  size_t i = ((size_t)blockIdx.x * 256 + threadIdx.x) * 8;
  f32x4 a = *(const f32x4*)(in + i);
  f32x4 b = *(const f32x4*)(in + i + 4);
  bf16x8 o;
#pragma unroll
  for (int j = 0; j < 4; ++j) { o[j] = f2bf(a[j]); o[4 + j] = f2bf(b[j]); }
  *(bf16x8*)(out + i) = o;
}

// ---------------------------------------------------------------------------
// in[R][C] fp32 -> out[C][R] bf16, 64x64 LDS tiles
__global__ __launch_bounds__(256) void transpose_cvt(const float* __restrict__ in,
                                                     short* __restrict__ out,
                                                     int R, int C) {
  __shared__ float t[64][65];
  const int tid = threadIdx.x;
  const int c0 = blockIdx.x * 64, r0 = blockIdx.y * 64;
#pragma unroll
  for (int i = 0; i < 16; ++i) {
    int idx = i * 256 + tid;
    int r = idx >> 6, c = idx & 63;
    t[r][c] = in[(size_t)(r0 + r) * C + c0 + c];
  }
  __syncthreads();
#pragma unroll
  for (int i = 0; i < 16; ++i) {
    int idx = i * 256 + tid;
    int cc = idx >> 6, rr = idx & 63;
    out[(size_t)(c0 + cc) * R + r0 + rr] = f2bf(t[rr][cc]);
  }
}

// ---------------------------------------------------------------------------
// v part of qkv bf16 [4096][6144] -> vt bf16 [b][h][128][2048]
__global__ __launch_bounds__(256) void transpose_v_bf(const short* __restrict__ qkv,
                                                      short* __restrict__ vt) {
  __shared__ short t[64][65];
  const int tid = threadIdx.x;
  const int d0 = blockIdx.x * 64;   // 0 or 64
  const int s0 = blockIdx.y * 64;   // 32 tiles
  const int bh = blockIdx.z;
  const int b = bh >> 4, h = bh & 15;
#pragma unroll
  for (int i = 0; i < 16; ++i) {
    int idx = i * 256 + tid;
    int r = idx >> 6, c = idx & 63;   // r = s-local, c = d-local
    t[r][c] = qkv[(size_t)(b * 2048 + s0 + r) * 6144 + 4096 + h * 128 + d0 + c];
  }
  __syncthreads();
#pragma unroll
  for (int i = 0; i < 16; ++i) {
    int idx = i * 256 + tid;
    int dd = idx >> 6, ss = idx & 63;
    vt[((size_t)(bh * 128 + d0 + dd)) * 2048 + s0 + ss] = t[ss][dd];
  }
}

// ---------------------------------------------------------------------------
// LayerNorm over full D=2048 for q and k slices of qkv bf16, write bf16.
// q output is pre-scaled by 1/sqrt(d_head) (folded attention scale).
__global__ __launch_bounds__(256) void ln_qk(const short* __restrict__ qkv,
                                             const float* __restrict__ qsc,
                                             const float* __restrict__ ksc,
                                             short* __restrict__ q_bf,
                                             short* __restrict__ k_bf) {
  __shared__ float redS[2][4], redQ[2][4];
  const int row = blockIdx.x, tid = threadIdx.x;
  const int lane = tid & 63, wave = tid >> 6;
  const short* base = qkv + (size_t)row * 6144;
#pragma unroll
  for (int part = 0; part < 2; ++part) {
    const short* p = base + part * 2048 + tid * 8;
    bf16x8 v8 = *(const bf16x8*)p;
    float f[8];
#pragma unroll
    for (int j = 0; j < 8; ++j) f[j] = bf2f(v8[j]);
    float s = 0.f, sq = 0.f;
#pragma unroll
    for (int j = 0; j < 8; ++j) { s += f[j]; sq += f[j] * f[j]; }
#pragma unroll
    for (int d = 1; d < 64; d <<= 1) { s += __shfl_xor(s, d); sq += __shfl_xor(sq, d); }
    if (lane == 0) { redS[part][wave] = s; redQ[part][wave] = sq; }
    __syncthreads();
    float tot  = redS[part][0] + redS[part][1] + redS[part][2] + redS[part][3];
    float totq = redQ[part][0] + redQ[part][1] + redQ[part][2] + redQ[part][3];
    float mean = tot * (1.f / 2048.f);
    float var  = totq * (1.f / 2048.f) - mean * mean;
    float rstd = rsqrtf(var + 1e-6f) * (part == 0 ? ATT_SCALE : 1.0f);
    const float* scp = (part == 0 ? qsc : ksc) + tid * 8;
    f32x4 s0 = *(const f32x4*)scp;
    f32x4 s1 = *(const f32x4*)(scp + 4);
    bf16x8 o;
#pragma unroll
    for (int j = 0; j < 4; ++j) {
      o[j]     = f2bf((f[j] - mean) * rstd * s0[j]);
      o[4 + j] = f2bf((f[4 + j] - mean) * rstd * s1[j]);
    }
    short* outp = (part == 0 ? q_bf : k_bf) + (size_t)row * 2048 + tid * 8;
    *(bf16x8*)outp = o;
  }
}

// ---------------------------------------------------------------------------
// C[M][N] = A[M][K] @ BT[N][K]^T + bias[N]; bf16 inputs, OutT out
// 128x128 tile, BK=64, 4 waves (2x2), 16x16x32 MFMA.
// 128B LDS rows XOR-swizzled: write slot (c&7) holds global chunk
// (c&7)^(row&7); read slot g^(row&7) yields chunk g. 2-way bank aliasing
// only (free, m136). Fragments loaded per-K-half to hold VGPR ~165.
template <typename OutT>
__global__ __launch_bounds__(256, 2) void gemm_bt_bias(const short* __restrict__ A,
                                                       const short* __restrict__ BT,
                                                       const float* __restrict__ bias,
                                                       OutT* __restrict__ C,
                                                       int M, int N, int K) {
  __shared__ alignas(16) short a_lds[128 * 64];
  __shared__ alignas(16) short b_lds[128 * 64];
  const int tid = threadIdx.x;
  const int lane = tid & 63, wave = tid >> 6;
  const int wr = wave >> 1, wc = wave & 1;
  const int tn = blockIdx.x, tm = blockIdx.y;
  const int r15 = lane & 15, hi = lane >> 4;

  const short* Ab = A + (size_t)tm * 128 * K;
  const short* Bb = BT + (size_t)tn * 128 * K;

  f32x4 acc[4][4];
  const f32x4 Z = {0.f, 0.f, 0.f, 0.f};
#pragma unroll
  for (int m = 0; m < 4; ++m)
#pragma unroll
    for (int n = 0; n < 4; ++n) acc[m][n] = Z;

  for (int k0 = 0; k0 < K; k0 += 64) {
    __syncthreads();
#pragma unroll
    for (int j = 0; j < 4; ++j) {
      int c = j * 256 + tid;              // 1024 slots of 8 elems
      int row = c >> 3;                   // 128 rows x 8 chunks
      int ch = (c & 7) ^ (row & 7);       // pre-swizzled source chunk
      async_copy16(&a_lds[c << 3], Ab + (size_t)row * K + k0 + (ch << 3));
      async_copy16(&b_lds[c << 3], Bb + (size_t)row * K + k0 + (ch << 3));
    }
    VMDRAIN;
    __syncthreads();
#pragma unroll
    for (int kk = 0; kk < 2; ++kk) {
      bf16x8 af[4], bfr[4];
#pragma unroll
      for (int m = 0; m < 4; ++m) {
        int row = wr * 64 + m * 16 + r15;
        af[m] = *(const bf16x8*)&a_lds[row * 64 + (((kk * 4 + hi) ^ (row & 7)) << 3)];
      }
#pragma unroll
      for (int n = 0; n < 4; ++n) {
        int row = wc * 64 + n * 16 + r15;
        bfr[n] = *(const bf16x8*)&b_lds[row * 64 + (((kk * 4 + hi) ^ (row & 7)) << 3)];
      }
#pragma unroll
      for (int m = 0; m < 4; ++m)
#pragma unroll
        for (int n = 0; n < 4; ++n)
          acc[m][n] = MFMA16(af[m], bfr[n], acc[m][n]);
    }
  }

  const int r0 = tm * 128 + wr * 64;
  const int c0 = tn * 128 + wc * 64;
#pragma unroll
  for (int n = 0; n < 4; ++n) {
    float bv = bias[c0 + n * 16 + r15];
#pragma unroll
    for (int m = 0; m < 4; ++m) {
#pragma unroll
      for (int r = 0; r < 4; ++r) {
        float val = acc[m][n][r] + bv;
        size_t idx = (size_t)(r0 + m * 16 + hi * 4 + r) * N + c0 + n * 16 + r15;
        if constexpr (sizeof(OutT) == 2) C[idx] = (OutT)f2bf(val);
        else                             C[idx] = val;
      }
    }
  }
}

// ---------------------------------------------------------------------------
// Flash attention: block = (qt, h, b), 4 waves x 16 q-rows, KV tile = 64
// R4-proven single-buffer staging, two barriers per tile. Math deltas:
// scale folded into q-LN, diag-peeled mask, cvt_pk P pack, MFMA-ones rowsum.
// q_bf/k_bf: [4096][2048] bf16 (col = h*128+dd); vt: [b][h][128][2048] bf16
__global__ __launch_bounds__(256) void attn_fwd(const short* __restrict__ q_bf,
                                                const short* __restrict__ k_bf,
                                                const short* __restrict__ vt,
                                                const float* __restrict__ abias,
                                                const int* __restrict__ amask,
                                                short* __restrict__ out_bf) {
  __shared__ alignas(16) short K_lds[64 * 128];
  __shared__ alignas(16) short V_lds[128 * 64];
  __shared__ alignas(16) short p_lds[4][16 * 64];
  __shared__ float bias_c[2048];

  const int tid = threadIdx.x, lane = tid & 63, wave = tid >> 6;
  const int qt = 31 - blockIdx.x;   // heavy (long) blocks dispatch first
  const int h = blockIdx.y, b = blockIdx.z;
  const int r15 = lane & 15, hi = lane >> 4;

  // combined ALiBi bias + padding-mask exclusion
  for (int i = tid; i < 2048; i += 256) {
    float bb = abias[h * 2048 + i];
    if (amask[b * 2048 + i] == 0) bb = -1e30f;
    bias_c[i] = bb;
  }

  // Q fragments held in registers (16 rows per wave); q pre-scaled by 1/sqrt(d)
  const int qrow = b * 2048 + qt * 64 + wave * 16 + r15;
  bf16x8 qf[4];
#pragma unroll
  for (int kb = 0; kb < 4; ++kb)
    qf[kb] = *(const bf16x8*)(q_bf + (size_t)qrow * 2048 + h * 128 + kb * 32 + hi * 8);

  f32x4 O[8];
  const f32x4 Z = {0.f, 0.f, 0.f, 0.f};
#pragma unroll
  for (int n = 0; n < 8; ++n) O[n] = Z;
  f32x4 Ol = Z;                 // running row-sum of exp (all cols identical)
  float m_run[4];
#pragma unroll
  for (int r = 0; r < 4; ++r) m_run[r] = -3e38f;

  const short one_bf = (short)0x3F80;  // bf16 1.0
  const bf16x8 ones_f = {one_bf, one_bf, one_bf, one_bf,
                         one_bf, one_bf, one_bf, one_bf};
  const int qg0 = qt * 64 + wave * 16 + hi * 4;
  const int ntiles = qt + 1;

  for (int kt = 0; kt < ntiles; ++kt) {
    __syncthreads();   // K_lds/V_lds free (prev tile fully consumed); bias_c ready

    // ---- stage K [64][128] and V^T [128][64], XOR-swizzled source ----
#pragma unroll
    for (int j = 0; j < 4; ++j) {
      int c = j * 256 + tid;
      int kr = c >> 4, kc = (c & 15) ^ (kr & 7);
      async_copy16(&K_lds[c << 3],
                   k_bf + (size_t)(b * 2048 + kt * 64 + kr) * 2048 + h * 128 + (kc << 3));
      int vr = c >> 3, vc = (c & 7) ^ (vr & 7);
      async_copy16(&V_lds[c << 3],
                   vt + ((size_t)((b * 16 + h) * 128 + vr)) * 2048 + kt * 64 + (vc << 3));
    }
    VMDRAIN;
    __syncthreads();

    // ---- QK^T: S[16q][64k] per wave ----
    f32x4 s[4];
#pragma unroll
    for (int ks = 0; ks < 4; ++ks) {
      s[ks] = Z;
#pragma unroll
      for (int kb = 0; kb < 4; ++kb) {
        int row = ks * 16 + r15;
        int ch = (kb * 4 + hi) ^ (row & 7);
        bf16x8 kf = *(const bf16x8*)&K_lds[row * 128 + ch * 8];
        s[ks] = MFMA16(qf[kb], kf, s[ks]);
      }
    }

    // ---- bias (+ causal mask only on the diagonal tile) ----
    if (kt == qt) {
#pragma unroll
      for (int ks = 0; ks < 4; ++ks) {
        int kg = kt * 64 + ks * 16 + r15;
        float bb = bias_c[kg];
#pragma unroll
        for (int r = 0; r < 4; ++r) {
          float v = s[ks][r] + bb;
          if (kg > qg0 + r) v = -1e30f;
          s[ks][r] = v;
        }
      }
    } else {
#pragma unroll
      for (int ks = 0; ks < 4; ++ks) {
        float bb = bias_c[kt * 64 + ks * 16 + r15];
#pragma unroll
        for (int r = 0; r < 4; ++r) s[ks][r] += bb;
      }
    }

    // ---- online softmax (rows live on 16-lane groups) ----
    float corr[4];
#pragma unroll
    for (int r = 0; r < 4; ++r) {
      float mx = fmaxf(fmaxf(s[0][r], s[1][r]), fmaxf(s[2][r], s[3][r]));
      mx = fmaxf(mx, __shfl_xor(mx, 1));
      mx = fmaxf(mx, __shfl_xor(mx, 2));
      mx = fmaxf(mx, __shfl_xor(mx, 4));
      mx = fmaxf(mx, __shfl_xor(mx, 8));
      float mn = fmaxf(m_run[r], mx);
      corr[r] = __expf(m_run[r] - mn);
      m_run[r] = mn;
#pragma unroll
      for (int ks = 0; ks < 4; ++ks) s[ks][r] = __expf(s[ks][r] - mn);
    }
#pragma unroll
    for (int r = 0; r < 4; ++r) {
      Ol[r] *= corr[r];
#pragma unroll
      for (int n = 0; n < 8; ++n) O[n][r] *= corr[r];
    }

    // ---- P -> per-wave LDS (swizzled) via cvt_pk, reload as A-fragments ----
    short* pw = &p_lds[wave][0];
#pragma unroll
    for (int r = 0; r < 4; ++r) {
      int q = hi * 4 + r;
      int qs = (q & 7) << 3;
      uint32_t pk0, pk1;
      asm("v_cvt_pk_bf16_f32 %0, %1, %2" : "=v"(pk0) : "v"(s[0][r]), "v"(s[1][r]));
      asm("v_cvt_pk_bf16_f32 %0, %1, %2" : "=v"(pk1) : "v"(s[2][r]), "v"(s[3][r]));
      pw[q * 64 + ((r15) ^ qs)]      = (short)pk0;
      pw[q * 64 + ((16 + r15) ^ qs)] = (short)(pk0 >> 16);
      pw[q * 64 + ((32 + r15) ^ qs)] = (short)pk1;
      pw[q * 64 + ((48 + r15) ^ qs)] = (short)(pk1 >> 16);
    }

    bf16x8 pf[2];
#pragma unroll
    for (int kb = 0; kb < 2; ++kb)
      pf[kb] = *(const bf16x8*)&pw[r15 * 64 + ((kb * 32 + hi * 8) ^ ((r15 & 7) << 3))];

    // ---- PV: O[16q][128d] += P @ V ; rowsum via MFMA with ones ----
#pragma unroll
    for (int n = 0; n < 8; ++n) {
#pragma unroll
      for (int kb = 0; kb < 2; ++kb) {
        int row = n * 16 + r15;
        int ch = (kb * 4 + hi) ^ (row & 7);
        bf16x8 vf = *(const bf16x8*)&V_lds[row * 64 + ch * 8];
        O[n] = MFMA16(pf[kb], vf, O[n]);
      }
    }
    Ol = MFMA16(pf[0], ones_f, Ol);
    Ol = MFMA16(pf[1], ones_f, Ol);
  }

  float inv[4];
#pragma unroll
  for (int r = 0; r < 4; ++r) inv[r] = 1.0f / Ol[r];
  const int orow = b * 2048 + qt * 64 + wave * 16;
#pragma unroll
  for (int n = 0; n < 8; ++n)
#pragma unroll
    for (int r = 0; r < 4; ++r)
      out_bf[(size_t)(orow + hi * 4 + r) * 2048 + h * 128 + n * 16 + r15] =
          f2bf(O[n][r] * inv[r]);
}

// ---------------------------------------------------------------------------
extern "C" void kernel_launch(void* const* d_in, const int* in_sizes, int n_in,
                              void* d_out, int out_size, void* d_ws, size_t ws_size,
                              hipStream_t stream) {
  const float* x     = (const float*)d_in[0];
  const float* abias = (const float*)d_in[1];
  const int*   amask = (const int*)d_in[2];
  const float* w_qkv = (const float*)d_in[3];
  const float* b_qkv = (const float*)d_in[4];
  const float* wo    = (const float*)d_in[5];
  const float* b_wo  = (const float*)d_in[6];
  const float* q_ln  = (const float*)d_in[7];
  const float* k_ln  = (const float*)d_in[8];
  float* out = (float*)d_out;

  char* ws = (char*)d_ws;
  short* x_bf   = (short*)(ws);                  // 16.78 MB  [4096][2048]
  short* wqkvT  = (short*)(ws + 16777216);       // 25.17 MB  [6144][2048]
  short* woT    = (short*)(ws + 41943040);       //  8.39 MB  [2048][2048]
  short* q_bf   = (short*)(ws + 50331648);       // 16.78 MB
  short* k_bf   = (short*)(ws + 67108864);       // 16.78 MB
  short* vt     = (short*)(ws + 83886080);       // 16.78 MB  [b][h][128][2048]
  short* out_bf = (short*)(ws + 100663296);      // 16.78 MB
  short* qkv_bf = (short*)(ws + 117440512);      // 50.33 MB  [4096][6144] bf16
  // total = 167,772,160 bytes

  cvt_f32_bf16<<<4096, 256, 0, stream>>>(x, x_bf);
  transpose_cvt<<<dim3(96, 32), 256, 0, stream>>>(w_qkv, wqkvT, 2048, 6144);
  transpose_cvt<<<dim3(32, 32), 256, 0, stream>>>(wo, woT, 2048, 2048);
  gemm_bt_bias<short><<<dim3(48, 32), 256, 0, stream>>>(x_bf, wqkvT, b_qkv, qkv_bf,
                                                        4096, 6144, 2048);
  ln_qk<<<4096, 256, 0, stream>>>(qkv_bf, q_ln, k_ln, q_bf, k_bf);
  transpose_v_bf<<<dim3(2, 32, 32), 256, 0, stream>>>(qkv_bf, vt);
  attn_fwd<<<dim3(32, 16, 2), 256, 0, stream>>>(q_bf, k_bf, vt, abias, amask, out_bf);
  gemm_bt_bias<float><<<dim3(16, 32), 256, 0, stream>>>(out_bf, woT, b_wo, out,
                                                        4096, 2048, 2048);
}

// Round 16
// 356.347 us; speedup vs baseline: 2.2147x; 1.0026x over previous
//
#include <hip/hip_runtime.h>
#include <stdint.h>
#include <stddef.h>

// ---------------------------------------------------------------------------
// FlaxMptAttention fused block for MI355X (gfx950)
// B=2, S=2048, D=2048, H=16, d_head=128
// Pipeline: cvt(x) / transpose-cvt(w_qkv, wo) -> QKV GEMM (bf16 out)
//           -> LN(q,k) -> transpose(v) -> flash attention -> out-proj GEMM
// R16: FINAL RE-LOCK of the thrice-proven build (R12/R14, 357.3us).
//      Session constraint ledger: attn_fwd is correct ONLY in this exact
//      form (6/6 restructure attempts failed correctness: R2,R3,R6,R9,R10,
//      R15 — including the guide-verified 2-phase recipe); 8-phase GEMM
//      rejected on grid-quantization arithmetic (384/64-block grids);
//      direct-global attn (R13) correct but 3.9x slower (scatter reads).
// ---------------------------------------------------------------------------

typedef __attribute__((ext_vector_type(8))) short bf16x8;
typedef __attribute__((ext_vector_type(4))) float f32x4;

#define MFMA16(a, b, c) __builtin_amdgcn_mfma_f32_16x16x32_bf16((a), (b), (c), 0, 0, 0)

__device__ __forceinline__ void async_copy16(void* lds, const void* g) {
  __builtin_amdgcn_global_load_lds(
      (const __attribute__((address_space(1))) void*)g,
      (__attribute__((address_space(3))) void*)lds, 16, 0, 0);
}

__device__ __forceinline__ short f2bf(float f) {
  union { float f; uint32_t u; } v; v.f = f;
  uint32_t r = (v.u + 0x7fffu + ((v.u >> 16) & 1u)) >> 16;
  return (short)(uint16_t)r;
}

__device__ __forceinline__ float bf2f(short s) {
  union { float f; uint32_t u; } v;
  v.u = ((uint32_t)(uint16_t)s) << 16;
  return v.f;
}

#define ATT_SCALE 0.08838834764831845f
#define VMDRAIN asm volatile("s_waitcnt vmcnt(0)" ::: "memory")

// ---------------------------------------------------------------------------
// elementwise fp32 -> bf16 (exact multiple of 2048 elems per block)
__global__ __launch_bounds__(256) void cvt_f32_bf16(const float* __restrict__ in,
                                                    short* __restrict__ out) {
  size_t i = ((size_t)blockIdx.x * 256 + threadIdx.x) * 8;
  f32x4 a = *(const f32x4*)(in + i);
  f32x4 b = *(const f32x4*)(in + i + 4);
  bf16x8 o;
#pragma unroll
  for (int j = 0; j < 4; ++j) { o[j] = f2bf(a[j]); o[4 + j] = f2bf(b[j]); }
  *(bf16x8*)(out + i) = o;
}

// ---------------------------------------------------------------------------
// in[R][C] fp32 -> out[C][R] bf16, 64x64 LDS tiles
__global__ __launch_bounds__(256) void transpose_cvt(const float* __restrict__ in,
                                                     short* __restrict__ out,
                                                     int R, int C) {
  __shared__ float t[64][65];
  const int tid = threadIdx.x;
  const int c0 = blockIdx.x * 64, r0 = blockIdx.y * 64;
#pragma unroll
  for (int i = 0; i < 16; ++i) {
    int idx = i * 256 + tid;
    int r = idx >> 6, c = idx & 63;
    t[r][c] = in[(size_t)(r0 + r) * C + c0 + c];
  }
  __syncthreads();
#pragma unroll
  for (int i = 0; i < 16; ++i) {
    int idx = i * 256 + tid;
    int cc = idx >> 6, rr = idx & 63;
    out[(size_t)(c0 + cc) * R + r0 + rr] = f2bf(t[rr][cc]);
  }
}

// ---------------------------------------------------------------------------
// v part of qkv bf16 [4096][6144] -> vt bf16 [b][h][128][2048]
__global__ __launch_bounds__(256) void transpose_v_bf(const short* __restrict__ qkv,
                                                      short* __restrict__ vt) {
  __shared__ short t[64][65];
  const int tid = threadIdx.x;
  const int d0 = blockIdx.x * 64;   // 0 or 64
  const int s0 = blockIdx.y * 64;   // 32 tiles
  const int bh = blockIdx.z;
  const int b = bh >> 4, h = bh & 15;
#pragma unroll
  for (int i = 0; i < 16; ++i) {
    int idx = i * 256 + tid;
    int r = idx >> 6, c = idx & 63;   // r = s-local, c = d-local
    t[r][c] = qkv[(size_t)(b * 2048 + s0 + r) * 6144 + 4096 + h * 128 + d0 + c];
  }
  __syncthreads();
#pragma unroll
  for (int i = 0; i < 16; ++i) {
    int idx = i * 256 + tid;
    int dd = idx >> 6, ss = idx & 63;
    vt[((size_t)(bh * 128 + d0 + dd)) * 2048 + s0 + ss] = t[ss][dd];
  }
}

// ---------------------------------------------------------------------------
// LayerNorm over full D=2048 for q and k slices of qkv bf16, write bf16.
// q output is pre-scaled by 1/sqrt(d_head) (folded attention scale).
__global__ __launch_bounds__(256) void ln_qk(const short* __restrict__ qkv,
                                             const float* __restrict__ qsc,
                                             const float* __restrict__ ksc,
                                             short* __restrict__ q_bf,
                                             short* __restrict__ k_bf) {
  __shared__ float redS[2][4], redQ[2][4];
  const int row = blockIdx.x, tid = threadIdx.x;
  const int lane = tid & 63, wave = tid >> 6;
  const short* base = qkv + (size_t)row * 6144;
#pragma unroll
  for (int part = 0; part < 2; ++part) {
    const short* p = base + part * 2048 + tid * 8;
    bf16x8 v8 = *(const bf16x8*)p;
    float f[8];
#pragma unroll
    for (int j = 0; j < 8; ++j) f[j] = bf2f(v8[j]);
    float s = 0.f, sq = 0.f;
#pragma unroll
    for (int j = 0; j < 8; ++j) { s += f[j]; sq += f[j] * f[j]; }
#pragma unroll
    for (int d = 1; d < 64; d <<= 1) { s += __shfl_xor(s, d); sq += __shfl_xor(sq, d); }
    if (lane == 0) { redS[part][wave] = s; redQ[part][wave] = sq; }
    __syncthreads();
    float tot  = redS[part][0] + redS[part][1] + redS[part][2] + redS[part][3];
    float totq = redQ[part][0] + redQ[part][1] + redQ[part][2] + redQ[part][3];
    float mean = tot * (1.f / 2048.f);
    float var  = totq * (1.f / 2048.f) - mean * mean;
    float rstd = rsqrtf(var + 1e-6f) * (part == 0 ? ATT_SCALE : 1.0f);
    const float* scp = (part == 0 ? qsc : ksc) + tid * 8;
    f32x4 s0 = *(const f32x4*)scp;
    f32x4 s1 = *(const f32x4*)(scp + 4);
    bf16x8 o;
#pragma unroll
    for (int j = 0; j < 4; ++j) {
      o[j]     = f2bf((f[j] - mean) * rstd * s0[j]);
      o[4 + j] = f2bf((f[4 + j] - mean) * rstd * s1[j]);
    }
    short* outp = (part == 0 ? q_bf : k_bf) + (size_t)row * 2048 + tid * 8;
    *(bf16x8*)outp = o;
  }
}

// ---------------------------------------------------------------------------
// C[M][N] = A[M][K] @ BT[N][K]^T + bias[N]; bf16 inputs, OutT out
// 128x128 tile, BK=64, 4 waves (2x2), 16x16x32 MFMA.
// 128B LDS rows XOR-swizzled: write slot (c&7) holds global chunk
// (c&7)^(row&7); read slot g^(row&7) yields chunk g. 2-way bank aliasing
// only (free, m136). Fragments loaded per-K-half to hold VGPR ~165.
template <typename OutT>
__global__ __launch_bounds__(256, 2) void gemm_bt_bias(const short* __restrict__ A,
                                                       const short* __restrict__ BT,
                                                       const float* __restrict__ bias,
                                                       OutT* __restrict__ C,
                                                       int M, int N, int K) {
  __shared__ alignas(16) short a_lds[128 * 64];
  __shared__ alignas(16) short b_lds[128 * 64];
  const int tid = threadIdx.x;
  const int lane = tid & 63, wave = tid >> 6;
  const int wr = wave >> 1, wc = wave & 1;
  const int tn = blockIdx.x, tm = blockIdx.y;
  const int r15 = lane & 15, hi = lane >> 4;

  const short* Ab = A + (size_t)tm * 128 * K;
  const short* Bb = BT + (size_t)tn * 128 * K;

  f32x4 acc[4][4];
  const f32x4 Z = {0.f, 0.f, 0.f, 0.f};
#pragma unroll
  for (int m = 0; m < 4; ++m)
#pragma unroll
    for (int n = 0; n < 4; ++n) acc[m][n] = Z;

  for (int k0 = 0; k0 < K; k0 += 64) {
    __syncthreads();
#pragma unroll
    for (int j = 0; j < 4; ++j) {
      int c = j * 256 + tid;              // 1024 slots of 8 elems
      int row = c >> 3;                   // 128 rows x 8 chunks
      int ch = (c & 7) ^ (row & 7);       // pre-swizzled source chunk
      async_copy16(&a_lds[c << 3], Ab + (size_t)row * K + k0 + (ch << 3));
      async_copy16(&b_lds[c << 3], Bb + (size_t)row * K + k0 + (ch << 3));
    }
    VMDRAIN;
    __syncthreads();
#pragma unroll
    for (int kk = 0; kk < 2; ++kk) {
      bf16x8 af[4], bfr[4];
#pragma unroll
      for (int m = 0; m < 4; ++m) {
        int row = wr * 64 + m * 16 + r15;
        af[m] = *(const bf16x8*)&a_lds[row * 64 + (((kk * 4 + hi) ^ (row & 7)) << 3)];
      }
#pragma unroll
      for (int n = 0; n < 4; ++n) {
        int row = wc * 64 + n * 16 + r15;
        bfr[n] = *(const bf16x8*)&b_lds[row * 64 + (((kk * 4 + hi) ^ (row & 7)) << 3)];
      }
#pragma unroll
      for (int m = 0; m < 4; ++m)
#pragma unroll
        for (int n = 0; n < 4; ++n)
          acc[m][n] = MFMA16(af[kk == 0 ? m : m], bfr[n], acc[m][n]);
    }
  }

  const int r0 = tm * 128 + wr * 64;
  const int c0 = tn * 128 + wc * 64;
#pragma unroll
  for (int n = 0; n < 4; ++n) {
    float bv = bias[c0 + n * 16 + r15];
#pragma unroll
    for (int m = 0; m < 4; ++m) {
#pragma unroll
      for (int r = 0; r < 4; ++r) {
        float val = acc[m][n][r] + bv;
        size_t idx = (size_t)(r0 + m * 16 + hi * 4 + r) * N + c0 + n * 16 + r15;
        if constexpr (sizeof(OutT) == 2) C[idx] = (OutT)f2bf(val);
        else                             C[idx] = val;
      }
    }
  }
}

// ---------------------------------------------------------------------------
// Flash attention: block = (qt, h, b), 4 waves x 16 q-rows, KV tile = 64
// R4-proven single-buffer staging, two barriers per tile. Math deltas:
// scale folded into q-LN, diag-peeled mask, cvt_pk P pack, MFMA-ones rowsum.
// q_bf/k_bf: [4096][2048] bf16 (col = h*128+dd); vt: [b][h][128][2048] bf16
__global__ __launch_bounds__(256) void attn_fwd(const short* __restrict__ q_bf,
                                                const short* __restrict__ k_bf,
                                                const short* __restrict__ vt,
                                                const float* __restrict__ abias,
                                                const int* __restrict__ amask,
                                                short* __restrict__ out_bf) {
  __shared__ alignas(16) short K_lds[64 * 128];
  __shared__ alignas(16) short V_lds[128 * 64];
  __shared__ alignas(16) short p_lds[4][16 * 64];
  __shared__ float bias_c[2048];

  const int tid = threadIdx.x, lane = tid & 63, wave = tid >> 6;
  const int qt = 31 - blockIdx.x;   // heavy (long) blocks dispatch first
  const int h = blockIdx.y, b = blockIdx.z;
  const int r15 = lane & 15, hi = lane >> 4;

  // combined ALiBi bias + padding-mask exclusion
  for (int i = tid; i < 2048; i += 256) {
    float bb = abias[h * 2048 + i];
    if (amask[b * 2048 + i] == 0) bb = -1e30f;
    bias_c[i] = bb;
  }

  // Q fragments held in registers (16 rows per wave); q pre-scaled by 1/sqrt(d)
  const int qrow = b * 2048 + qt * 64 + wave * 16 + r15;
  bf16x8 qf[4];
#pragma unroll
  for (int kb = 0; kb < 4; ++kb)
    qf[kb] = *(const bf16x8*)(q_bf + (size_t)qrow * 2048 + h * 128 + kb * 32 + hi * 8);

  f32x4 O[8];
  const f32x4 Z = {0.f, 0.f, 0.f, 0.f};
#pragma unroll
  for (int n = 0; n < 8; ++n) O[n] = Z;
  f32x4 Ol = Z;                 // running row-sum of exp (all cols identical)
  float m_run[4];
#pragma unroll
  for (int r = 0; r < 4; ++r) m_run[r] = -3e38f;

  const short one_bf = (short)0x3F80;  // bf16 1.0
  const bf16x8 ones_f = {one_bf, one_bf, one_bf, one_bf,
                         one_bf, one_bf, one_bf, one_bf};
  const int qg0 = qt * 64 + wave * 16 + hi * 4;
  const int ntiles = qt + 1;

  for (int kt = 0; kt < ntiles; ++kt) {
    __syncthreads();   // K_lds/V_lds free (prev tile fully consumed); bias_c ready

    // ---- stage K [64][128] and V^T [128][64], XOR-swizzled source ----
#pragma unroll
    for (int j = 0; j < 4; ++j) {
      int c = j * 256 + tid;
      int kr = c >> 4, kc = (c & 15) ^ (kr & 7);
      async_copy16(&K_lds[c << 3],
                   k_bf + (size_t)(b * 2048 + kt * 64 + kr) * 2048 + h * 128 + (kc << 3));
      int vr = c >> 3, vc = (c & 7) ^ (vr & 7);
      async_copy16(&V_lds[c << 3],
                   vt + ((size_t)((b * 16 + h) * 128 + vr)) * 2048 + kt * 64 + (vc << 3));
    }
    VMDRAIN;
    __syncthreads();

    // ---- QK^T: S[16q][64k] per wave ----
    f32x4 s[4];
#pragma unroll
    for (int ks = 0; ks < 4; ++ks) {
      s[ks] = Z;
#pragma unroll
      for (int kb = 0; kb < 4; ++kb) {
        int row = ks * 16 + r15;
        int ch = (kb * 4 + hi) ^ (row & 7);
        bf16x8 kf = *(const bf16x8*)&K_lds[row * 128 + ch * 8];
        s[ks] = MFMA16(qf[kb], kf, s[ks]);
      }
    }

    // ---- bias (+ causal mask only on the diagonal tile) ----
    if (kt == qt) {
#pragma unroll
      for (int ks = 0; ks < 4; ++ks) {
        int kg = kt * 64 + ks * 16 + r15;
        float bb = bias_c[kg];
#pragma unroll
        for (int r = 0; r < 4; ++r) {
          float v = s[ks][r] + bb;
          if (kg > qg0 + r) v = -1e30f;
          s[ks][r] = v;
        }
      }
    } else {
#pragma unroll
      for (int ks = 0; ks < 4; ++ks) {
        float bb = bias_c[kt * 64 + ks * 16 + r15];
#pragma unroll
        for (int r = 0; r < 4; ++r) s[ks][r] += bb;
      }
    }

    // ---- online softmax (rows live on 16-lane groups) ----
    float corr[4];
#pragma unroll
    for (int r = 0; r < 4; ++r) {
      float mx = fmaxf(fmaxf(s[0][r], s[1][r]), fmaxf(s[2][r], s[3][r]));
      mx = fmaxf(mx, __shfl_xor(mx, 1));
      mx = fmaxf(mx, __shfl_xor(mx, 2));
      mx = fmaxf(mx, __shfl_xor(mx, 4));
      mx = fmaxf(mx, __shfl_xor(mx, 8));
      float mn = fmaxf(m_run[r], mx);
      corr[r] = __expf(m_run[r] - mn);
      m_run[r] = mn;
#pragma unroll
      for (int ks = 0; ks < 4; ++ks) s[ks][r] = __expf(s[ks][r] - mn);
    }
#pragma unroll
    for (int r = 0; r < 4; ++r) {
      Ol[r] *= corr[r];
#pragma unroll
      for (int n = 0; n < 8; ++n) O[n][r] *= corr[r];
    }

    // ---- P -> per-wave LDS (swizzled) via cvt_pk, reload as A-fragments ----
    short* pw = &p_lds[wave][0];
#pragma unroll
    for (int r = 0; r < 4; ++r) {
      int q = hi * 4 + r;
      int qs = (q & 7) << 3;
      uint32_t pk0, pk1;
      asm("v_cvt_pk_bf16_f32 %0, %1, %2" : "=v"(pk0) : "v"(s[0][r]), "v"(s[1][r]));
      asm("v_cvt_pk_bf16_f32 %0, %1, %2" : "=v"(pk1) : "v"(s[2][r]), "v"(s[3][r]));
      pw[q * 64 + ((r15) ^ qs)]      = (short)pk0;
      pw[q * 64 + ((16 + r15) ^ qs)] = (short)(pk0 >> 16);
      pw[q * 64 + ((32 + r15) ^ qs)] = (short)pk1;
      pw[q * 64 + ((48 + r15) ^ qs)] = (short)(pk1 >> 16);
    }

    bf16x8 pf[2];
#pragma unroll
    for (int kb = 0; kb < 2; ++kb)
      pf[kb] = *(const bf16x8*)&pw[r15 * 64 + ((kb * 32 + hi * 8) ^ ((r15 & 7) << 3))];

    // ---- PV: O[16q][128d] += P @ V ; rowsum via MFMA with ones ----
#pragma unroll
    for (int n = 0; n < 8; ++n) {
#pragma unroll
      for (int kb = 0; kb < 2; ++kb) {
        int row = n * 16 + r15;
        int ch = (kb * 4 + hi) ^ (row & 7);
        bf16x8 vf = *(const bf16x8*)&V_lds[row * 64 + ch * 8];
        O[n] = MFMA16(pf[kb], vf, O[n]);
      }
    }
    Ol = MFMA16(pf[0], ones_f, Ol);
    Ol = MFMA16(pf[1], ones_f, Ol);
  }

  float inv[4];
#pragma unroll
  for (int r = 0; r < 4; ++r) inv[r] = 1.0f / Ol[r];
  const int orow = b * 2048 + qt * 64 + wave * 16;
#pragma unroll
  for (int n = 0; n < 8; ++n)
#pragma unroll
    for (int r = 0; r < 4; ++r)
      out_bf[(size_t)(orow + hi * 4 + r) * 2048 + h * 128 + n * 16 + r15] =
          f2bf(O[n][r] * inv[r]);
}

// ---------------------------------------------------------------------------
extern "C" void kernel_launch(void* const* d_in, const int* in_sizes, int n_in,
                              void* d_out, int out_size, void* d_ws, size_t ws_size,
                              hipStream_t stream) {
  const float* x     = (const float*)d_in[0];
  const float* abias = (const float*)d_in[1];
  const int*   amask = (const int*)d_in[2];
  const float* w_qkv = (const float*)d_in[3];
  const float* b_qkv = (const float*)d_in[4];
  const float* wo    = (const float*)d_in[5];
  const float* b_wo  = (const float*)d_in[6];
  const float* q_ln  = (const float*)d_in[7];
  const float* k_ln  = (const float*)d_in[8];
  float* out = (float*)d_out;

  char* ws = (char*)d_ws;
  short* x_bf   = (short*)(ws);                  // 16.78 MB  [4096][2048]
  short* wqkvT  = (short*)(ws + 16777216);       // 25.17 MB  [6144][2048]
  short* woT    = (short*)(ws + 41943040);       //  8.39 MB  [2048][2048]
  short* q_bf   = (short*)(ws + 50331648);       // 16.78 MB
  short* k_bf   = (short*)(ws + 67108864);       // 16.78 MB
  short* vt     = (short*)(ws + 83886080);       // 16.78 MB  [b][h][128][2048]
  short* out_bf = (short*)(ws + 100663296);      // 16.78 MB
  short* qkv_bf = (short*)(ws + 117440512);      // 50.33 MB  [4096][6144] bf16
  // total = 167,772,160 bytes

  cvt_f32_bf16<<<4096, 256, 0, stream>>>(x, x_bf);
  transpose_cvt<<<dim3(96, 32), 256, 0, stream>>>(w_qkv, wqkvT, 2048, 6144);
  transpose_cvt<<<dim3(32, 32), 256, 0, stream>>>(wo, woT, 2048, 2048);
  gemm_bt_bias<short><<<dim3(48, 32), 256, 0, stream>>>(x_bf, wqkvT, b_qkv, qkv_bf,
                                                        4096, 6144, 2048);
  ln_qk<<<4096, 256, 0, stream>>>(qkv_bf, q_ln, k_ln, q_bf, k_bf);
  transpose_v_bf<<<dim3(2, 32, 32), 256, 0, stream>>>(qkv_bf, vt);
  attn_fwd<<<dim3(32, 16, 2), 256, 0, stream>>>(q_bf, k_bf, vt, abias, amask, out_bf);
  gemm_bt_bias<float><<<dim3(16, 32), 256, 0, stream>>>(out_bf, woT, b_wo, out,
                                                        4096, 2048, 2048);
}